// Round 1
// baseline (785.773 us; speedup 1.0000x reference)
//
#include <hip/hip_runtime.h>

#define L 21
#define NVOX 4096
#define ITERS 5
#define JCHUNK 64

// ---------------------------------------------------------------------------
// Setup: features f = [pos/67, rgb/3] (SoA, 6 x N), halfsq = 0.5*|f|^2,
// and the separable spatial normalizer norm_sp(z,y,x) = h(z)h(y)h(x).
// ---------------------------------------------------------------------------
__global__ __launch_bounds__(256) void setup_kernel(
    const float* __restrict__ img, float* __restrict__ feat,
    float* __restrict__ halfsq, float* __restrict__ norm_sp)
{
    int i = blockIdx.x * 256 + threadIdx.x;
    int z = i >> 8, y = (i >> 4) & 15, x = i & 15;
    const float ia = 1.0f / 67.0f, ib = 1.0f / 3.0f;
    float f0 = (float)z * ia, f1 = (float)y * ia, f2 = (float)x * ia;
    float f3 = img[i] * ib, f4 = img[NVOX + i] * ib, f5 = img[2 * NVOX + i] * ib;
    feat[0 * NVOX + i] = f0; feat[1 * NVOX + i] = f1; feat[2 * NVOX + i] = f2;
    feat[3 * NVOX + i] = f3; feat[4 * NVOX + i] = f4; feat[5 * NVOX + i] = f5;
    halfsq[i] = 0.5f * (f0 * f0 + f1 * f1 + f2 * f2 + f3 * f3 + f4 * f4 + f5 * f5);
    float hz = 0.f, hy = 0.f, hx = 0.f;
    for (int b = 0; b < 16; b++) {
        float dz = (float)(z - b), dy = (float)(y - b), dx = (float)(x - b);
        hz += __expf(-0.5f * dz * dz);
        hy += __expf(-0.5f * dy * dy);
        hx += __expf(-0.5f * dx * dx);
    }
    norm_sp[i] = hz * hy * hx;
}

// ---------------------------------------------------------------------------
// Build bilateral kernel matrix K[j][i] = exp(min(f_j.f_i - hs_j - hs_i, 0)).
// Grid: (4, 4096); thread -> 4 consecutive columns (float4 store).
// ---------------------------------------------------------------------------
__global__ __launch_bounds__(256) void build_kbi(
    const float* __restrict__ feat, const float* __restrict__ halfsq,
    float* __restrict__ K)
{
    int j = blockIdx.y;
    int i0 = blockIdx.x * 1024 + threadIdx.x * 4;
    float fj0 = feat[j], fj1 = feat[NVOX + j], fj2 = feat[2 * NVOX + j];
    float fj3 = feat[3 * NVOX + j], fj4 = feat[4 * NVOX + j], fj5 = feat[5 * NVOX + j];
    float hj = halfsq[j];
    float4 a0 = *(const float4*)(feat + 0 * NVOX + i0);
    float4 a1 = *(const float4*)(feat + 1 * NVOX + i0);
    float4 a2 = *(const float4*)(feat + 2 * NVOX + i0);
    float4 a3 = *(const float4*)(feat + 3 * NVOX + i0);
    float4 a4 = *(const float4*)(feat + 4 * NVOX + i0);
    float4 a5 = *(const float4*)(feat + 5 * NVOX + i0);
    float4 hs = *(const float4*)(halfsq + i0);
    float4 o;
    o.x = __expf(fminf(fj0*a0.x + fj1*a1.x + fj2*a2.x + fj3*a3.x + fj4*a4.x + fj5*a5.x - hj - hs.x, 0.f));
    o.y = __expf(fminf(fj0*a0.y + fj1*a1.y + fj2*a2.y + fj3*a3.y + fj4*a4.y + fj5*a5.y - hj - hs.y, 0.f));
    o.z = __expf(fminf(fj0*a0.z + fj1*a1.z + fj2*a2.z + fj3*a3.z + fj4*a4.z + fj5*a5.z - hj - hs.z, 0.f));
    o.w = __expf(fminf(fj0*a0.w + fj1*a1.w + fj2*a2.w + fj3*a3.w + fj4*a4.w + fj5*a5.w - hj - hs.w, 0.f));
    *(float4*)(K + (size_t)j * NVOX + i0) = o;
}

// ---------------------------------------------------------------------------
// Softmax over L per voxel; also zero the bilateral accumulators for this
// iteration (saves separate memset dispatches).
// ---------------------------------------------------------------------------
__global__ __launch_bounds__(256) void softmax_zero(
    const float* __restrict__ cur, float* __restrict__ q,
    float* __restrict__ bi_acc, float* __restrict__ norm_acc)
{
    int i = blockIdx.x * 256 + threadIdx.x;
    float v[L];
    float m = -1e30f;
#pragma unroll
    for (int l = 0; l < L; l++) { v[l] = cur[l * NVOX + i]; m = fmaxf(m, v[l]); }
    float s = 0.f;
#pragma unroll
    for (int l = 0; l < L; l++) { v[l] = __expf(v[l] - m); s += v[l]; }
    float inv = 1.f / s;
#pragma unroll
    for (int l = 0; l < L; l++) {
        q[l * NVOX + i] = v[l] * inv;
        bi_acc[l * NVOX + i] = 0.f;
    }
    norm_acc[i] = 0.f;
}

// ---------------------------------------------------------------------------
// Bilateral filtering: bi_acc[l][i] += sum_j q[l][j] * K[j][i] and
// norm_acc[i] += sum_j K[j][i].  Grid (4 i-tiles, 64 j-chunks) x 256 thr.
// Thread owns 4 consecutive columns (float4 K loads, coalesced 1KB/wave).
// q chunk staged transposed in LDS, rows padded to 24 floats (96B, 16B
// aligned) so the 21 broadcast reads merge into ds_read_b128.
// ---------------------------------------------------------------------------
__global__ __launch_bounds__(256) void bilateral_kernel(
    const float* __restrict__ K, const float* __restrict__ q,
    float* __restrict__ bi_acc, float* __restrict__ norm_acc)
{
    __shared__ float qT[JCHUNK][24];
    int tid = threadIdx.x;
    int i0 = blockIdx.x * 1024 + tid * 4;
    int j0 = blockIdx.y * JCHUNK;
    for (int e = tid; e < L * JCHUNK; e += 256) {
        int l = e >> 6;      // e / 64
        int jj = e & 63;     // coalesced over jj for fixed l
        qT[jj][l] = q[l * NVOX + j0 + jj];
    }
    __syncthreads();
    float4 acc[L];
#pragma unroll
    for (int l = 0; l < L; l++) acc[l] = make_float4(0.f, 0.f, 0.f, 0.f);
    float4 nacc = make_float4(0.f, 0.f, 0.f, 0.f);
#pragma unroll 4
    for (int jj = 0; jj < JCHUNK; jj++) {
        float4 kv = *(const float4*)(K + (size_t)(j0 + jj) * NVOX + i0);
        nacc.x += kv.x; nacc.y += kv.y; nacc.z += kv.z; nacc.w += kv.w;
        const float* qr = qT[jj];
#pragma unroll
        for (int l = 0; l < L; l++) {
            float ql = qr[l];
            acc[l].x = fmaf(ql, kv.x, acc[l].x);
            acc[l].y = fmaf(ql, kv.y, acc[l].y);
            acc[l].z = fmaf(ql, kv.z, acc[l].z);
            acc[l].w = fmaf(ql, kv.w, acc[l].w);
        }
    }
#pragma unroll
    for (int l = 0; l < L; l++) {
        atomicAdd(&bi_acc[l * NVOX + i0 + 0], acc[l].x);
        atomicAdd(&bi_acc[l * NVOX + i0 + 1], acc[l].y);
        atomicAdd(&bi_acc[l * NVOX + i0 + 2], acc[l].z);
        atomicAdd(&bi_acc[l * NVOX + i0 + 3], acc[l].w);
    }
    atomicAdd(&norm_acc[i0 + 0], nacc.x);
    atomicAdd(&norm_acc[i0 + 1], nacc.y);
    atomicAdd(&norm_acc[i0 + 2], nacc.z);
    atomicAdd(&norm_acc[i0 + 3], nacc.w);
}

// ---------------------------------------------------------------------------
// Spatial filtering: exact separable 3D Gaussian conv (full 16 taps per axis)
// per label.  One block per label; whole 16^3 volume lives in LDS.
// Output is UNNORMALIZED; combine divides by norm_sp.
// ---------------------------------------------------------------------------
__global__ __launch_bounds__(256) void spatial_kernel(
    const float* __restrict__ q, float* __restrict__ sp)
{
    __shared__ float buf[NVOX];
    __shared__ float tmp[NVOX];
    __shared__ float g[16];
    int l = blockIdx.x, tid = threadIdx.x;
    if (tid < 16) g[tid] = __expf(-0.5f * (float)(tid * tid));
    for (int k = 0; k < 16; k++) buf[tid + 256 * k] = q[l * NVOX + tid + 256 * k];
    __syncthreads();
    // x pass (stride 1)
    for (int k = 0; k < 16; k++) {
        int idx = tid + 256 * k;
        int x = idx & 15, base = idx & ~15;
        float s = 0.f;
#pragma unroll
        for (int b = 0; b < 16; b++) {
            int d = x - b; d = d < 0 ? -d : d;
            s += g[d] * buf[base + b];
        }
        tmp[idx] = s;
    }
    __syncthreads();
    // y pass (stride 16)
    for (int k = 0; k < 16; k++) {
        int idx = tid + 256 * k;
        int y = (idx >> 4) & 15, base = idx & ~(15 << 4);
        float s = 0.f;
#pragma unroll
        for (int b = 0; b < 16; b++) {
            int d = y - b; d = d < 0 ? -d : d;
            s += g[d] * tmp[base + (b << 4)];
        }
        buf[idx] = s;
    }
    __syncthreads();
    // z pass (stride 256), write out
    for (int k = 0; k < 16; k++) {
        int idx = tid + 256 * k;
        int z = idx >> 8, base = idx & 255;
        float s = 0.f;
#pragma unroll
        for (int b = 0; b < 16; b++) {
            int d = z - b; d = d < 0 ? -d : d;
            s += g[d] * buf[base + (b << 8)];
        }
        sp[l * NVOX + idx] = s;
    }
}

// ---------------------------------------------------------------------------
// Combine: normalize both filter outputs, apply the three L x L matrices,
// add unary, write cur (or final output).
// ---------------------------------------------------------------------------
__global__ __launch_bounds__(256) void combine_kernel(
    const float* __restrict__ sp, const float* __restrict__ bi_acc,
    const float* __restrict__ norm_sp, const float* __restrict__ norm_acc,
    const float* __restrict__ Wsp, const float* __restrict__ Wbi,
    const float* __restrict__ Wc, const float* __restrict__ unary,
    float* __restrict__ dst)
{
    __shared__ float wsp[L * L], wbi[L * L], wc[L * L];
    int tid = threadIdx.x;
    for (int e = tid; e < L * L; e += 256) {
        wsp[e] = Wsp[e]; wbi[e] = Wbi[e]; wc[e] = Wc[e];
    }
    __syncthreads();
    int i = blockIdx.x * 256 + tid;
    float rsp = 1.f / norm_sp[i];
    float rbi = 1.f / norm_acc[i];
    float vsp[L], vbi[L], t[L];
#pragma unroll
    for (int l = 0; l < L; l++) {
        vsp[l] = sp[l * NVOX + i] * rsp;
        vbi[l] = bi_acc[l * NVOX + i] * rbi;
    }
#pragma unroll
    for (int m = 0; m < L; m++) {
        float s = 0.f;
#pragma unroll
        for (int k = 0; k < L; k++)
            s += wsp[m * L + k] * vsp[k] + wbi[m * L + k] * vbi[k];
        t[m] = s;
    }
#pragma unroll
    for (int l = 0; l < L; l++) {
        float s = 0.f;
#pragma unroll
        for (int m = 0; m < L; m++) s += wc[l * L + m] * t[m];
        dst[l * NVOX + i] = s + unary[l * NVOX + i];
    }
}

extern "C" void kernel_launch(void* const* d_in, const int* in_sizes, int n_in,
                              void* d_out, int out_size, void* d_ws, size_t ws_size,
                              hipStream_t stream) {
    const float* image  = (const float*)d_in[0];
    const float* logits = (const float*)d_in[1];
    const float* Wsp    = (const float*)d_in[2];
    const float* Wbi    = (const float*)d_in[3];
    const float* Wc     = (const float*)d_in[4];
    float* out = (float*)d_out;

    char* ws = (char*)d_ws;
    float* K       = (float*)ws; ws += (size_t)NVOX * NVOX * sizeof(float);   // 64 MiB
    float* feat    = (float*)ws; ws += (size_t)6 * NVOX * sizeof(float);
    float* halfsq  = (float*)ws; ws += (size_t)NVOX * sizeof(float);
    float* norm_sp = (float*)ws; ws += (size_t)NVOX * sizeof(float);
    float* q       = (float*)ws; ws += (size_t)L * NVOX * sizeof(float);
    float* cur     = (float*)ws; ws += (size_t)L * NVOX * sizeof(float);
    float* sp      = (float*)ws; ws += (size_t)L * NVOX * sizeof(float);
    float* bi      = (float*)ws; ws += (size_t)L * NVOX * sizeof(float);
    float* nbi     = (float*)ws; ws += (size_t)NVOX * sizeof(float);

    setup_kernel<<<16, 256, 0, stream>>>(image, feat, halfsq, norm_sp);
    build_kbi<<<dim3(4, NVOX), 256, 0, stream>>>(feat, halfsq, K);

    const float* src = logits;
    for (int it = 0; it < ITERS; it++) {
        softmax_zero<<<16, 256, 0, stream>>>(src, q, bi, nbi);
        bilateral_kernel<<<dim3(4, 64), 256, 0, stream>>>(K, q, bi, nbi);
        spatial_kernel<<<L, 256, 0, stream>>>(q, sp);
        float* dst = (it == ITERS - 1) ? out : cur;
        combine_kernel<<<16, 256, 0, stream>>>(sp, bi, norm_sp, nbi,
                                               Wsp, Wbi, Wc, logits, dst);
        src = cur;
    }
}

// Round 2
// 354.735 us; speedup vs baseline: 2.2151x; 2.2151x over previous
//
#include <hip/hip_runtime.h>

#define L 21
#define NVOX 4096
#define ITERS 5
#define NU 210      // monomials of degree <= 4 in 6 vars
#define UPAD 224
#define UC 42       // u per G2 chunk
#define NCH 5       // u chunks (5*42 = 210)

// ---------------------------------------------------------------------------
// Setup: features f = [pos/67, rgb/3] (SoA 6xN), hs = 0.5|f|^2, separable
// spatial normalizer nsp = h(z)h(y)h(x); block 0 folds W1=Wc@Wsp, W2=Wc@Wbi.
// ---------------------------------------------------------------------------
__global__ __launch_bounds__(256) void setup_kernel(
    const float* __restrict__ img, const float* __restrict__ Wsp,
    const float* __restrict__ Wbi, const float* __restrict__ Wc,
    float* __restrict__ feat, float* __restrict__ hs,
    float* __restrict__ nsp, float* __restrict__ W1, float* __restrict__ W2)
{
    int tid = threadIdx.x;
    int i = blockIdx.x * 256 + tid;
    int z = i >> 8, y = (i >> 4) & 15, x = i & 15;
    const float ia = 1.0f / 67.0f, ib = 1.0f / 3.0f;
    float f0 = (float)z * ia, f1 = (float)y * ia, f2 = (float)x * ia;
    float f3 = img[i] * ib, f4 = img[NVOX + i] * ib, f5 = img[2 * NVOX + i] * ib;
    feat[0 * NVOX + i] = f0; feat[1 * NVOX + i] = f1; feat[2 * NVOX + i] = f2;
    feat[3 * NVOX + i] = f3; feat[4 * NVOX + i] = f4; feat[5 * NVOX + i] = f5;
    hs[i] = 0.5f * (f0 * f0 + f1 * f1 + f2 * f2 + f3 * f3 + f4 * f4 + f5 * f5);
    float hz = 0.f, hy = 0.f, hx = 0.f;
    for (int b = 0; b < 16; b++) {
        float dz = (float)(z - b), dy = (float)(y - b), dx = (float)(x - b);
        hz += __expf(-0.5f * dz * dz);
        hy += __expf(-0.5f * dy * dy);
        hx += __expf(-0.5f * dx * dx);
    }
    nsp[i] = hz * hy * hx;
    if (blockIdx.x == 0) {
        for (int e = tid; e < L * L; e += 256) {
            int r = e / L, c = e % L;
            float s1 = 0.f, s2 = 0.f;
            for (int k = 0; k < L; k++) {
                float wc = Wc[r * L + k];
                s1 = fmaf(wc, Wsp[k * L + c], s1);
                s2 = fmaf(wc, Wbi[k * L + c], s2);
            }
            W1[e] = s1; W2[e] = s2;
        }
    }
}

// ---------------------------------------------------------------------------
// Phi[u][i] = exp(-hs_i) * f_i^alpha(u)  (deg<=4 monomials, fixed order);
// block 0 also writes the multinomial coefficient table cu[u] = 1/alpha!.
// ---------------------------------------------------------------------------
__global__ __launch_bounds__(256) void phi_build(
    const float* __restrict__ feat, const float* __restrict__ hs,
    float* __restrict__ Phi, float* __restrict__ cu)
{
    int tid = threadIdx.x;
    int i = blockIdx.x * 256 + tid;
    float p[6][5];
#pragma unroll
    for (int c = 0; c < 6; c++) {
        float f = feat[c * NVOX + i];
        p[c][0] = 1.f;
#pragma unroll
        for (int k = 1; k < 5; k++) p[c][k] = p[c][k - 1] * f;
    }
    float e0 = __expf(-hs[i]);
    int u = 0;
#pragma unroll
    for (int a0 = 0; a0 <= 4; a0++)
#pragma unroll
    for (int a1 = 0; a1 <= 4 - a0; a1++)
#pragma unroll
    for (int a2 = 0; a2 <= 4 - a0 - a1; a2++)
#pragma unroll
    for (int a3 = 0; a3 <= 4 - a0 - a1 - a2; a3++)
#pragma unroll
    for (int a4 = 0; a4 <= 4 - a0 - a1 - a2 - a3; a4++)
#pragma unroll
    for (int a5 = 0; a5 <= 4 - a0 - a1 - a2 - a3 - a4; a5++) {
        Phi[(size_t)u * NVOX + i] =
            e0 * p[0][a0] * p[1][a1] * p[2][a2] * p[3][a3] * p[4][a4] * p[5][a5];
        u++;
    }
    if (blockIdx.x == 0) {
        const float invf[5] = {1.f, 1.f, 0.5f, 1.f / 6.f, 1.f / 24.f};
        float mine = 0.f;
        int v = 0;
#pragma unroll
        for (int a0 = 0; a0 <= 4; a0++)
#pragma unroll
        for (int a1 = 0; a1 <= 4 - a0; a1++)
#pragma unroll
        for (int a2 = 0; a2 <= 4 - a0 - a1; a2++)
#pragma unroll
        for (int a3 = 0; a3 <= 4 - a0 - a1 - a2; a3++)
#pragma unroll
        for (int a4 = 0; a4 <= 4 - a0 - a1 - a2 - a3; a4++)
#pragma unroll
        for (int a5 = 0; a5 <= 4 - a0 - a1 - a2 - a3 - a4; a5++) {
            if (v == tid)
                mine = invf[a0] * invf[a1] * invf[a2] * invf[a3] * invf[a4] * invf[a5];
            v++;
        }
        if (tid < NU) cu[tid] = mine;
    }
}

// ---------------------------------------------------------------------------
// sv: A2 row 21 = cu[u] * sum_i Phi[u][i]  (bilateral normalizer coeffs;
// iteration-independent, written once).
// ---------------------------------------------------------------------------
__global__ __launch_bounds__(64) void sv_kernel(
    const float* __restrict__ Phi, const float* __restrict__ cu,
    float* __restrict__ A2)
{
    int u = blockIdx.x, tid = threadIdx.x;
    const float* row = Phi + (size_t)u * NVOX;
    float s = 0.f;
    for (int ii = tid; ii < NVOX; ii += 64) s += row[ii];
#pragma unroll
    for (int off = 32; off >= 1; off >>= 1) s += __shfl_xor(s, off);
    if (tid == 0) A2[L * UPAD + u] = cu[u] * s;
}

// ---------------------------------------------------------------------------
// Softmax over L per voxel -> q; also zero A2 rows 0..20 for this iteration.
// ---------------------------------------------------------------------------
__global__ __launch_bounds__(256) void softmax_zero(
    const float* __restrict__ cur, float* __restrict__ q, float* __restrict__ A2)
{
    int tid = threadIdx.x;
    int i = blockIdx.x * 256 + tid;
    float v[L];
    float m = -1e30f;
#pragma unroll
    for (int l = 0; l < L; l++) { v[l] = cur[l * NVOX + i]; m = fmaxf(m, v[l]); }
    float s = 0.f;
#pragma unroll
    for (int l = 0; l < L; l++) { v[l] = __expf(v[l] - m); s += v[l]; }
    float inv = 1.f / s;
#pragma unroll
    for (int l = 0; l < L; l++) q[l * NVOX + i] = v[l] * inv;
    for (int e = blockIdx.x * 256 + tid; e < L * UPAD; e += 4096) A2[e] = 0.f;
}

// ---------------------------------------------------------------------------
// G1: M[m][u] = sum_i q[m][i] Phi[u][i]; epilogue folds cu and W2:
// A2[m'][u] += cu[u] * sum_m W2[m'][m] M[m][u].  Grid (210 u, 4 i-splits).
// ---------------------------------------------------------------------------
__global__ __launch_bounds__(64) void g1_kernel(
    const float* __restrict__ q, const float* __restrict__ Phi,
    const float* __restrict__ cu, const float* __restrict__ W2,
    float* __restrict__ A2)
{
    int u = blockIdx.x;
    int i0 = blockIdx.y * 1024;
    int tid = threadIdx.x;
    float acc[L];
#pragma unroll
    for (int m = 0; m < L; m++) acc[m] = 0.f;
    const float* ph = Phi + (size_t)u * NVOX + i0;
    const float* qq = q + i0;
    for (int ii = tid; ii < 1024; ii += 64) {
        float p = ph[ii];
#pragma unroll
        for (int m = 0; m < L; m++)
            acc[m] = fmaf(qq[m * NVOX + ii], p, acc[m]);
    }
#pragma unroll
    for (int off = 32; off >= 1; off >>= 1)
#pragma unroll
        for (int m = 0; m < L; m++)
            acc[m] += __shfl_xor(acc[m], off);
    if (tid < L) {
        float dot = 0.f;
#pragma unroll
        for (int m = 0; m < L; m++)
            dot = fmaf(W2[tid * L + m], acc[m], dot);
        atomicAdd(&A2[tid * UPAD + u], cu[u] * dot);
    }
}

// ---------------------------------------------------------------------------
// G2: part[uc][m][i] = sum_{u in chunk uc} A2[m][u] * Phi[u][i]  (m=0..21,
// row 21 = normalizer).  Plain coalesced stores, no atomics.
// ---------------------------------------------------------------------------
__global__ __launch_bounds__(256) void g2_kernel(
    const float* __restrict__ Phi, const float* __restrict__ A2,
    float* __restrict__ part)
{
    __shared__ float sA[UC][24];
    int tid = threadIdx.x;
    int uc = blockIdx.y;
    int u0 = uc * UC;
    int i = blockIdx.x * 256 + tid;
    for (int e = tid; e < UC * 24; e += 256) {
        int uu = e / 24, m = e % 24;
        sA[uu][m] = (m < 22) ? A2[m * UPAD + u0 + uu] : 0.f;
    }
    __syncthreads();
    float4 acc[6];
#pragma unroll
    for (int j = 0; j < 6; j++) acc[j] = make_float4(0.f, 0.f, 0.f, 0.f);
    for (int uu = 0; uu < UC; uu++) {
        float pphi = Phi[(size_t)(u0 + uu) * NVOX + i];
        const float4* row = (const float4*)sA[uu];
#pragma unroll
        for (int j = 0; j < 6; j++) {
            float4 a = row[j];
            acc[j].x = fmaf(a.x, pphi, acc[j].x);
            acc[j].y = fmaf(a.y, pphi, acc[j].y);
            acc[j].z = fmaf(a.z, pphi, acc[j].z);
            acc[j].w = fmaf(a.w, pphi, acc[j].w);
        }
    }
#pragma unroll
    for (int j = 0; j < 6; j++) {
        float vals[4] = {acc[j].x, acc[j].y, acc[j].z, acc[j].w};
#pragma unroll
        for (int c = 0; c < 4; c++) {
            int m = 4 * j + c;
            if (m < 22) part[(size_t)(uc * 22 + m) * NVOX + i] = vals[c];
        }
    }
}

// ---------------------------------------------------------------------------
// Spatial filtering: exact separable 3D Gaussian (16 taps/axis) per label.
// One block per label, 1024 threads, volume in LDS. Unnormalized output.
// ---------------------------------------------------------------------------
__global__ __launch_bounds__(1024) void spatial_kernel(
    const float* __restrict__ q, float* __restrict__ sp)
{
    __shared__ float buf[NVOX];
    __shared__ float tmp[NVOX];
    __shared__ float g[16];
    int l = blockIdx.x, tid = threadIdx.x;
    if (tid < 16) g[tid] = __expf(-0.5f * (float)(tid * tid));
    for (int k = 0; k < 4; k++) buf[tid + 1024 * k] = q[l * NVOX + tid + 1024 * k];
    __syncthreads();
    for (int k = 0; k < 4; k++) {
        int idx = tid + 1024 * k;
        int x = idx & 15, base = idx & ~15;
        float s = 0.f;
#pragma unroll
        for (int b = 0; b < 16; b++) {
            int d = x - b; d = d < 0 ? -d : d;
            s += g[d] * buf[base + b];
        }
        tmp[idx] = s;
    }
    __syncthreads();
    for (int k = 0; k < 4; k++) {
        int idx = tid + 1024 * k;
        int y = (idx >> 4) & 15, base = idx & ~(15 << 4);
        float s = 0.f;
#pragma unroll
        for (int b = 0; b < 16; b++) {
            int d = y - b; d = d < 0 ? -d : d;
            s += g[d] * tmp[base + (b << 4)];
        }
        buf[idx] = s;
    }
    __syncthreads();
    for (int k = 0; k < 4; k++) {
        int idx = tid + 1024 * k;
        int z = idx >> 8, base = idx & 255;
        float s = 0.f;
#pragma unroll
        for (int b = 0; b < 16; b++) {
            int d = z - b; d = d < 0 ? -d : d;
            s += g[d] * buf[base + (b << 8)];
        }
        sp[l * NVOX + idx] = s;
    }
}

// ---------------------------------------------------------------------------
// Combine: sum G2 partials (row 21 = bilateral normalizer), normalize both
// paths, spatial side through W1 = Wc@Wsp (bilateral side already has W2
// folded in), add unary.
// ---------------------------------------------------------------------------
__global__ __launch_bounds__(256) void combine_kernel(
    const float* __restrict__ sp, const float* __restrict__ part,
    const float* __restrict__ nsp, const float* __restrict__ W1,
    const float* __restrict__ unary, float* __restrict__ dst)
{
    __shared__ float w1[L * L];
    int tid = threadIdx.x;
    for (int e = tid; e < L * L; e += 256) w1[e] = W1[e];
    __syncthreads();
    int i = blockIdx.x * 256 + tid;
    float b[22];
#pragma unroll
    for (int m = 0; m < 22; m++) {
        float s = 0.f;
#pragma unroll
        for (int c = 0; c < NCH; c++) s += part[(size_t)(c * 22 + m) * NVOX + i];
        b[m] = s;
    }
    float rbi = 1.f / b[21];
    float rsp = 1.f / nsp[i];
    float spn[L];
#pragma unroll
    for (int m = 0; m < L; m++) spn[m] = sp[m * NVOX + i] * rsp;
#pragma unroll
    for (int l = 0; l < L; l++) {
        float s = b[l] * rbi;
#pragma unroll
        for (int m = 0; m < L; m++) s = fmaf(w1[l * L + m], spn[m], s);
        dst[l * NVOX + i] = s + unary[l * NVOX + i];
    }
}

extern "C" void kernel_launch(void* const* d_in, const int* in_sizes, int n_in,
                              void* d_out, int out_size, void* d_ws, size_t ws_size,
                              hipStream_t stream) {
    const float* image  = (const float*)d_in[0];
    const float* logits = (const float*)d_in[1];
    const float* Wsp    = (const float*)d_in[2];
    const float* Wbi    = (const float*)d_in[3];
    const float* Wc     = (const float*)d_in[4];
    float* out = (float*)d_out;

    char* ws = (char*)d_ws;
    float* Phi  = (float*)ws; ws += (size_t)NU * NVOX * sizeof(float);      // 3.44 MB
    float* part = (float*)ws; ws += (size_t)NCH * 22 * NVOX * sizeof(float);// 1.80 MB
    float* feat = (float*)ws; ws += (size_t)6 * NVOX * sizeof(float);
    float* hs   = (float*)ws; ws += (size_t)NVOX * sizeof(float);
    float* nsp  = (float*)ws; ws += (size_t)NVOX * sizeof(float);
    float* q    = (float*)ws; ws += (size_t)L * NVOX * sizeof(float);
    float* cur  = (float*)ws; ws += (size_t)L * NVOX * sizeof(float);
    float* sp   = (float*)ws; ws += (size_t)L * NVOX * sizeof(float);
    float* A2   = (float*)ws; ws += (size_t)22 * UPAD * sizeof(float);
    float* cu   = (float*)ws; ws += (size_t)256 * sizeof(float);
    float* W1   = (float*)ws; ws += (size_t)L * L * sizeof(float);
    float* W2   = (float*)ws; ws += (size_t)L * L * sizeof(float);

    setup_kernel<<<16, 256, 0, stream>>>(image, Wsp, Wbi, Wc, feat, hs, nsp, W1, W2);
    phi_build<<<16, 256, 0, stream>>>(feat, hs, Phi, cu);
    sv_kernel<<<NU, 64, 0, stream>>>(Phi, cu, A2);

    const float* src = logits;
    for (int it = 0; it < ITERS; it++) {
        softmax_zero<<<16, 256, 0, stream>>>(src, q, A2);
        g1_kernel<<<dim3(NU, 4), 64, 0, stream>>>(q, Phi, cu, W2, A2);
        g2_kernel<<<dim3(16, NCH), 256, 0, stream>>>(Phi, A2, part);
        spatial_kernel<<<L, 1024, 0, stream>>>(q, sp);
        float* dst = (it == ITERS - 1) ? out : cur;
        combine_kernel<<<16, 256, 0, stream>>>(sp, part, nsp, W1, logits, dst);
        src = cur;
    }
}

// Round 3
// 234.098 us; speedup vs baseline: 3.3566x; 1.5153x over previous
//
#include <hip/hip_runtime.h>

#define L 21
#define NVOX 4096
#define ITERS 5
#define NU 210      // monomials of degree <= 4 in 6 vars
#define UPAD 224    // Phi rows padded (rows 210..223 are zero)
#define VPB 32      // voxels per block in fused g2_combine
#define NSPLIT 8    // u-range splits per voxel
#define USPL 28     // u per split (8*28 = 224)

// ---------------------------------------------------------------------------
// Setup: features f = [pos/67, rgb/3] (SoA 6xN), hs = 0.5|f|^2, separable
// spatial normalizer nsp = h(z)h(y)h(x); block 0 folds W1=Wc@Wsp, W2=Wc@Wbi.
// ---------------------------------------------------------------------------
__global__ __launch_bounds__(256) void setup_kernel(
    const float* __restrict__ img, const float* __restrict__ Wsp,
    const float* __restrict__ Wbi, const float* __restrict__ Wc,
    float* __restrict__ feat, float* __restrict__ hs,
    float* __restrict__ nsp, float* __restrict__ W1, float* __restrict__ W2)
{
    int tid = threadIdx.x;
    int i = blockIdx.x * 256 + tid;
    int z = i >> 8, y = (i >> 4) & 15, x = i & 15;
    const float ia = 1.0f / 67.0f, ib = 1.0f / 3.0f;
    float f0 = (float)z * ia, f1 = (float)y * ia, f2 = (float)x * ia;
    float f3 = img[i] * ib, f4 = img[NVOX + i] * ib, f5 = img[2 * NVOX + i] * ib;
    feat[0 * NVOX + i] = f0; feat[1 * NVOX + i] = f1; feat[2 * NVOX + i] = f2;
    feat[3 * NVOX + i] = f3; feat[4 * NVOX + i] = f4; feat[5 * NVOX + i] = f5;
    hs[i] = 0.5f * (f0 * f0 + f1 * f1 + f2 * f2 + f3 * f3 + f4 * f4 + f5 * f5);
    float hz = 0.f, hy = 0.f, hx = 0.f;
    for (int b = 0; b < 16; b++) {
        float dz = (float)(z - b), dy = (float)(y - b), dx = (float)(x - b);
        hz += __expf(-0.5f * dz * dz);
        hy += __expf(-0.5f * dy * dy);
        hx += __expf(-0.5f * dx * dx);
    }
    nsp[i] = hz * hy * hx;
    if (blockIdx.x == 0) {
        for (int e = tid; e < L * L; e += 256) {
            int r = e / L, c = e % L;
            float s1 = 0.f, s2 = 0.f;
            for (int k = 0; k < L; k++) {
                float wc = Wc[r * L + k];
                s1 = fmaf(wc, Wsp[k * L + c], s1);
                s2 = fmaf(wc, Wbi[k * L + c], s2);
            }
            W1[e] = s1; W2[e] = s2;
        }
    }
}

// ---------------------------------------------------------------------------
// Phi[u][i] = exp(-hs_i) * f_i^alpha(u)  (deg<=4 monomials, fixed order);
// rows 210..223 zero-padded.  Block 0 writes cu[u] = 1/alpha! (0 beyond NU).
// ---------------------------------------------------------------------------
__global__ __launch_bounds__(256) void phi_build(
    const float* __restrict__ feat, const float* __restrict__ hs,
    float* __restrict__ Phi, float* __restrict__ cu)
{
    int tid = threadIdx.x;
    int i = blockIdx.x * 256 + tid;
    float p[6][5];
#pragma unroll
    for (int c = 0; c < 6; c++) {
        float f = feat[c * NVOX + i];
        p[c][0] = 1.f;
#pragma unroll
        for (int k = 1; k < 5; k++) p[c][k] = p[c][k - 1] * f;
    }
    float e0 = __expf(-hs[i]);
    int u = 0;
#pragma unroll
    for (int a0 = 0; a0 <= 4; a0++)
#pragma unroll
    for (int a1 = 0; a1 <= 4 - a0; a1++)
#pragma unroll
    for (int a2 = 0; a2 <= 4 - a0 - a1; a2++)
#pragma unroll
    for (int a3 = 0; a3 <= 4 - a0 - a1 - a2; a3++)
#pragma unroll
    for (int a4 = 0; a4 <= 4 - a0 - a1 - a2 - a3; a4++)
#pragma unroll
    for (int a5 = 0; a5 <= 4 - a0 - a1 - a2 - a3 - a4; a5++) {
        Phi[(size_t)u * NVOX + i] =
            e0 * p[0][a0] * p[1][a1] * p[2][a2] * p[3][a3] * p[4][a4] * p[5][a5];
        u++;
    }
#pragma unroll
    for (int uz = NU; uz < UPAD; uz++) Phi[(size_t)uz * NVOX + i] = 0.f;
    if (blockIdx.x == 0) {
        const float invf[5] = {1.f, 1.f, 0.5f, 1.f / 6.f, 1.f / 24.f};
        float mine = 0.f;   // stays 0 for tid >= NU
        int v = 0;
#pragma unroll
        for (int a0 = 0; a0 <= 4; a0++)
#pragma unroll
        for (int a1 = 0; a1 <= 4 - a0; a1++)
#pragma unroll
        for (int a2 = 0; a2 <= 4 - a0 - a1; a2++)
#pragma unroll
        for (int a3 = 0; a3 <= 4 - a0 - a1 - a2; a3++)
#pragma unroll
        for (int a4 = 0; a4 <= 4 - a0 - a1 - a2 - a3; a4++)
#pragma unroll
        for (int a5 = 0; a5 <= 4 - a0 - a1 - a2 - a3 - a4; a5++) {
            if (v == tid)
                mine = invf[a0] * invf[a1] * invf[a2] * invf[a3] * invf[a4] * invf[a5];
            v++;
        }
        cu[tid] = mine;
    }
}

// ---------------------------------------------------------------------------
// sv: A2 row 21 (normalizer coeffs) = cu[u] * sum_i Phi[u][i]; grid UPAD so
// padded entries get exact zeros.  Iteration-independent, written once.
// ---------------------------------------------------------------------------
__global__ __launch_bounds__(64) void sv_kernel(
    const float* __restrict__ Phi, const float* __restrict__ cu,
    float* __restrict__ A2)
{
    int u = blockIdx.x, tid = threadIdx.x;
    const float* row = Phi + (size_t)u * NVOX;
    float s = 0.f;
    for (int ii = tid; ii < NVOX; ii += 64) s += row[ii];
#pragma unroll
    for (int off = 32; off >= 1; off >>= 1) s += __shfl_xor(s, off);
    if (tid == 0) A2[L * UPAD + u] = cu[u] * s;
}

// ---------------------------------------------------------------------------
// Softmax over L per voxel -> q; also zero A2 rows 0..20 for this iteration.
// ---------------------------------------------------------------------------
__global__ __launch_bounds__(128) void softmax_zero(
    const float* __restrict__ cur, float* __restrict__ q, float* __restrict__ A2)
{
    int tid = threadIdx.x;
    int i = blockIdx.x * 128 + tid;
    float v[L];
    float m = -1e30f;
#pragma unroll
    for (int l = 0; l < L; l++) { v[l] = cur[l * NVOX + i]; m = fmaxf(m, v[l]); }
    float s = 0.f;
#pragma unroll
    for (int l = 0; l < L; l++) { v[l] = __expf(v[l] - m); s += v[l]; }
    float inv = 1.f / s;
#pragma unroll
    for (int l = 0; l < L; l++) q[l * NVOX + i] = v[l] * inv;
    for (int e = i; e < L * UPAD; e += 4096) A2[e] = 0.f;
}

// ---------------------------------------------------------------------------
// G1: M[m][u] = sum_i q[m][i] Phi[u][i]; epilogue folds cu and W2:
// A2[m'][u] += cu[u] * sum_m W2[m'][m] M[m][u].  Grid (210 u, 4 i-splits).
// ---------------------------------------------------------------------------
__global__ __launch_bounds__(64) void g1_kernel(
    const float* __restrict__ q, const float* __restrict__ Phi,
    const float* __restrict__ cu, const float* __restrict__ W2,
    float* __restrict__ A2)
{
    int u = blockIdx.x;
    int i0 = blockIdx.y * 1024;
    int tid = threadIdx.x;
    float acc[L];
#pragma unroll
    for (int m = 0; m < L; m++) acc[m] = 0.f;
    const float* ph = Phi + (size_t)u * NVOX + i0;
    const float* qq = q + i0;
    for (int ii = tid; ii < 1024; ii += 64) {
        float p = ph[ii];
#pragma unroll
        for (int m = 0; m < L; m++)
            acc[m] = fmaf(qq[m * NVOX + ii], p, acc[m]);
    }
#pragma unroll
    for (int off = 32; off >= 1; off >>= 1)
#pragma unroll
        for (int m = 0; m < L; m++)
            acc[m] += __shfl_xor(acc[m], off);
    if (tid < L) {
        float dot = 0.f;
#pragma unroll
        for (int m = 0; m < L; m++)
            dot = fmaf(W2[tid * L + m], acc[m], dot);
        atomicAdd(&A2[tid * UPAD + u], cu[u] * dot);
    }
}

// ---------------------------------------------------------------------------
// Spatial filtering: exact separable 3D Gaussian (16 taps/axis) per label.
// One block per label, 1024 threads, volume in LDS. Unnormalized output.
// ---------------------------------------------------------------------------
__global__ __launch_bounds__(1024) void spatial_kernel(
    const float* __restrict__ q, float* __restrict__ sp)
{
    __shared__ float buf[NVOX];
    __shared__ float tmp[NVOX];
    __shared__ float g[16];
    int l = blockIdx.x, tid = threadIdx.x;
    if (tid < 16) g[tid] = __expf(-0.5f * (float)(tid * tid));
    for (int k = 0; k < 4; k++) buf[tid + 1024 * k] = q[l * NVOX + tid + 1024 * k];
    __syncthreads();
    for (int k = 0; k < 4; k++) {
        int idx = tid + 1024 * k;
        int x = idx & 15, base = idx & ~15;
        float s = 0.f;
#pragma unroll
        for (int b = 0; b < 16; b++) {
            int d = x - b; d = d < 0 ? -d : d;
            s += g[d] * buf[base + b];
        }
        tmp[idx] = s;
    }
    __syncthreads();
    for (int k = 0; k < 4; k++) {
        int idx = tid + 1024 * k;
        int y = (idx >> 4) & 15, base = idx & ~(15 << 4);
        float s = 0.f;
#pragma unroll
        for (int b = 0; b < 16; b++) {
            int d = y - b; d = d < 0 ? -d : d;
            s += g[d] * tmp[base + (b << 4)];
        }
        buf[idx] = s;
    }
    __syncthreads();
    for (int k = 0; k < 4; k++) {
        int idx = tid + 1024 * k;
        int z = idx >> 8, base = idx & 255;
        float s = 0.f;
#pragma unroll
        for (int b = 0; b < 16; b++) {
            int d = z - b; d = d < 0 ? -d : d;
            s += g[d] * buf[base + (b << 8)];
        }
        sp[l * NVOX + idx] = s;
    }
}

// ---------------------------------------------------------------------------
// Fused G2 + combine: b[m][i] = sum_u A2[m][u] Phi[u][i] (m=0..21, row 21 =
// bilateral normalizer), then dst = b[0..20]/b[21] + W1 @ (sp/nsp) + unary.
// Block: 256 thr = 32 voxels x 8 u-splits of 28; LDS tree reduction.
// red layout [22][8][32] -> bank = voxel, 2-way (free).  No atomics.
// ---------------------------------------------------------------------------
__global__ __launch_bounds__(256) void g2_combine(
    const float* __restrict__ Phi, const float* __restrict__ A2,
    const float* __restrict__ sp, const float* __restrict__ nsp,
    const float* __restrict__ W1, const float* __restrict__ unary,
    float* __restrict__ dst)
{
    __shared__ float sA[22 * UPAD];            // 19.3 KB
    __shared__ float red[22][NSPLIT][VPB];     // 22.0 KB
    __shared__ float sw1[L * L];
    __shared__ float sspn[VPB][22];
    int tid = threadIdx.x;
    int v = tid & (VPB - 1);
    int s = tid >> 5;
    int i = blockIdx.x * VPB + v;
    for (int e = tid; e < 22 * UPAD; e += 256) sA[e] = A2[e];
    for (int e = tid; e < L * L; e += 256) sw1[e] = W1[e];
    __syncthreads();
    float acc[22];
#pragma unroll
    for (int m = 0; m < 22; m++) acc[m] = 0.f;
    int u0 = s * USPL;
    for (int uu = 0; uu < USPL; uu++) {
        float p = Phi[(size_t)(u0 + uu) * NVOX + i];
#pragma unroll
        for (int m = 0; m < 22; m++)
            acc[m] = fmaf(sA[m * UPAD + u0 + uu], p, acc[m]);
    }
#pragma unroll
    for (int m = 0; m < 22; m++) red[m][s][v] = acc[m];
    float rsp = 1.f / nsp[i];
    for (int m = s; m < L; m += NSPLIT)
        sspn[v][m] = sp[m * NVOX + i] * rsp;
    __syncthreads();
    float b21 = 0.f;
#pragma unroll
    for (int ss = 0; ss < NSPLIT; ss++) b21 += red[21][ss][v];
    float rbi = 1.f / b21;
    for (int l = s; l < L; l += NSPLIT) {
        float bl = 0.f;
#pragma unroll
        for (int ss = 0; ss < NSPLIT; ss++) bl += red[l][ss][v];
        float r = bl * rbi;
#pragma unroll
        for (int m = 0; m < L; m++) r = fmaf(sw1[l * L + m], sspn[v][m], r);
        dst[l * NVOX + i] = r + unary[l * NVOX + i];
    }
}

extern "C" void kernel_launch(void* const* d_in, const int* in_sizes, int n_in,
                              void* d_out, int out_size, void* d_ws, size_t ws_size,
                              hipStream_t stream) {
    const float* image  = (const float*)d_in[0];
    const float* logits = (const float*)d_in[1];
    const float* Wsp    = (const float*)d_in[2];
    const float* Wbi    = (const float*)d_in[3];
    const float* Wc     = (const float*)d_in[4];
    float* out = (float*)d_out;

    char* ws = (char*)d_ws;
    float* Phi  = (float*)ws; ws += (size_t)UPAD * NVOX * sizeof(float);   // 3.67 MB
    float* feat = (float*)ws; ws += (size_t)6 * NVOX * sizeof(float);
    float* hs   = (float*)ws; ws += (size_t)NVOX * sizeof(float);
    float* nsp  = (float*)ws; ws += (size_t)NVOX * sizeof(float);
    float* q    = (float*)ws; ws += (size_t)L * NVOX * sizeof(float);
    float* cur  = (float*)ws; ws += (size_t)L * NVOX * sizeof(float);
    float* sp   = (float*)ws; ws += (size_t)L * NVOX * sizeof(float);
    float* A2   = (float*)ws; ws += (size_t)22 * UPAD * sizeof(float);
    float* cu   = (float*)ws; ws += (size_t)256 * sizeof(float);
    float* W1   = (float*)ws; ws += (size_t)L * L * sizeof(float);
    float* W2   = (float*)ws; ws += (size_t)L * L * sizeof(float);

    setup_kernel<<<16, 256, 0, stream>>>(image, Wsp, Wbi, Wc, feat, hs, nsp, W1, W2);
    phi_build<<<16, 256, 0, stream>>>(feat, hs, Phi, cu);
    sv_kernel<<<UPAD, 64, 0, stream>>>(Phi, cu, A2);

    const float* src = logits;
    for (int it = 0; it < ITERS; it++) {
        softmax_zero<<<32, 128, 0, stream>>>(src, q, A2);
        g1_kernel<<<dim3(NU, 4), 64, 0, stream>>>(q, Phi, cu, W2, A2);
        spatial_kernel<<<L, 1024, 0, stream>>>(q, sp);
        float* dst = (it == ITERS - 1) ? out : cur;
        g2_combine<<<128, 256, 0, stream>>>(Phi, A2, sp, nsp, W1, logits, dst);
        src = cur;
    }
}